// Round 3
// baseline (388.465 us; speedup 1.0000x reference)
//
#include <hip/hip_runtime.h>
#include <hip/hip_bf16.h>

#define NB 8
#define C1 512
#define C2 256
#define HWSZ 4096
#define BN_EPS 1e-5f

typedef __hip_bfloat16 bf16;
typedef __hip_bfloat162 bf162;

static __device__ inline float b2f(bf16 h) { return __bfloat162float(h); }

// pack 4 floats -> 4 bf16 (8 bytes)
static __device__ inline uint2 pack4(float a, float b, float c, float d) {
  union { uint2 u; bf162 h[2]; } pk;
  pk.h[0] = __float22bfloat162_rn(make_float2(a, b));
  pk.h[1] = __float22bfloat162_rn(make_float2(c, d));
  return pk.u;
}

// ---------------------------------------------------------------------------
// K0: transpose w_change [256][512] -> wchT [512][256]; w_cc1 likewise.
// ---------------------------------------------------------------------------
__global__ __launch_bounds__(256) void k0_transpose(
    const float* __restrict__ wch, const float* __restrict__ wcc1,
    float* __restrict__ wchT, float* __restrict__ wcc1T) {
  int idx = blockIdx.x * 256 + threadIdx.x;      // 0 .. 262143
  int which = idx >> 17;                          // 0: wch, 1: wcc1
  int r = idx & 131071;
  int ci = r >> 8;                                // 0..511
  int co = r & 255;                               // 0..255
  const float* s = which ? wcc1 : wch;
  float* d = which ? wcc1T : wchT;
  d[ci * 256 + co] = s[co * 512 + ci];
}

// ---------------------------------------------------------------------------
// K1: fused maxpool2x2 + conv1x1 (+bias): x1 [8][512][128][128] -> x1c(bf16)
// tile 32 m x 256 co, K=512, BK=8; 256 thr, 4x8 register tile each.
// ---------------------------------------------------------------------------
__global__ __launch_bounds__(256) void k1_pool_conv(
    const float* __restrict__ x1, const float* __restrict__ wT /*[512][256]*/,
    const float* __restrict__ bch, bf16* __restrict__ x1c) {
  __shared__ float As[8][32];
  __shared__ float Ws[8][256];
  const int tid = threadIdx.x;
  const int m0 = blockIdx.x * 32;
  const int n = m0 >> 12;
  const int hw0 = m0 & 4095;
  const int h = hw0 >> 6;
  const int w0 = hw0 & 63;
  const int tmq = tid & 7;
  const int tcq = tid >> 3;
  const int skk = tid >> 5;
  const int smm = tid & 31;

  float acc[4][8];
#pragma unroll
  for (int i = 0; i < 4; ++i)
#pragma unroll
    for (int j = 0; j < 8; ++j) acc[i][j] = 0.f;

  const size_t x1base = ((size_t)n * C1 * 16384) + (size_t)(2 * h) * 128 + (size_t)(2 * (w0 + smm));

  for (int k0 = 0; k0 < C1; k0 += 8) {
    const size_t cioff = (size_t)(k0 + skk) * 16384;
    const float2 a0 = *(const float2*)(x1 + x1base + cioff);
    const float2 a1 = *(const float2*)(x1 + x1base + cioff + 128);
    const float aval = fmaxf(fmaxf(a0.x, a0.y), fmaxf(a1.x, a1.y));
    float wv[8];
#pragma unroll
    for (int r = 0; r < 8; ++r) wv[r] = wT[(size_t)(k0 + r) * 256 + tid];
    __syncthreads();
    As[skk][smm] = aval;
#pragma unroll
    for (int r = 0; r < 8; ++r) Ws[r][tid] = wv[r];
    __syncthreads();
#pragma unroll
    for (int kk = 0; kk < 8; ++kk) {
      const float4 a  = *(const float4*)&As[kk][tmq << 2];
      const float4 b0 = *(const float4*)&Ws[kk][tcq << 3];
      const float4 b1 = *(const float4*)&Ws[kk][(tcq << 3) + 4];
      const float av[4] = {a.x, a.y, a.z, a.w};
      const float bv[8] = {b0.x, b0.y, b0.z, b0.w, b1.x, b1.y, b1.z, b1.w};
#pragma unroll
      for (int i = 0; i < 4; ++i)
#pragma unroll
        for (int j = 0; j < 8; ++j) acc[i][j] = fmaf(av[i], bv[j], acc[i][j]);
    }
  }

#pragma unroll
  for (int j = 0; j < 8; ++j) {
    const int co = (tcq << 3) + j;
    const float b = bch[co];
    *(uint2*)&x1c[((size_t)(n * C2 + co)) * HWSZ + hw0 + (tmq << 2)] =
        pack4(acc[0][j] + b, acc[1][j] + b, acc[2][j] + b, acc[3][j] + b);
  }
}

// ---------------------------------------------------------------------------
// K2: fused concat(x1c,x2) + conv1x1 + BN + ReLU -> xbn (fp32, lives in d_out)
// ---------------------------------------------------------------------------
__global__ __launch_bounds__(256) void k2_cc1_bn_relu(
    const bf16* __restrict__ x1c, const float* __restrict__ x2,
    const float* __restrict__ wT /*[512][256]*/,
    const float* __restrict__ gamma, const float* __restrict__ beta,
    const float* __restrict__ mean, const float* __restrict__ var,
    float* __restrict__ xbn) {
  __shared__ float As[8][32];
  __shared__ float Ws[8][256];
  const int tid = threadIdx.x;
  const int m0 = blockIdx.x * 32;
  const int n = m0 >> 12;
  const int hw0 = m0 & 4095;
  const int tmq = tid & 7;
  const int tcq = tid >> 3;
  const int skk = tid >> 5;
  const int smm = tid & 31;

  float acc[4][8];
#pragma unroll
  for (int i = 0; i < 4; ++i)
#pragma unroll
    for (int j = 0; j < 8; ++j) acc[i][j] = 0.f;

  for (int k0 = 0; k0 < 512; k0 += 8) {
    const int ci = k0 + skk;
    float aval;
    if (ci < 256) {
      aval = b2f(x1c[((size_t)(n * C2 + ci)) * HWSZ + hw0 + smm]);
    } else {
      aval = x2[((size_t)(n * C2 + (ci - 256))) * HWSZ + hw0 + smm];
    }
    float wv[8];
#pragma unroll
    for (int r = 0; r < 8; ++r) wv[r] = wT[(size_t)(k0 + r) * 256 + tid];
    __syncthreads();
    As[skk][smm] = aval;
#pragma unroll
    for (int r = 0; r < 8; ++r) Ws[r][tid] = wv[r];
    __syncthreads();
#pragma unroll
    for (int kk = 0; kk < 8; ++kk) {
      const float4 a  = *(const float4*)&As[kk][tmq << 2];
      const float4 b0 = *(const float4*)&Ws[kk][tcq << 3];
      const float4 b1 = *(const float4*)&Ws[kk][(tcq << 3) + 4];
      const float av[4] = {a.x, a.y, a.z, a.w};
      const float bv[8] = {b0.x, b0.y, b0.z, b0.w, b1.x, b1.y, b1.z, b1.w};
#pragma unroll
      for (int i = 0; i < 4; ++i)
#pragma unroll
        for (int j = 0; j < 8; ++j) acc[i][j] = fmaf(av[i], bv[j], acc[i][j]);
    }
  }

#pragma unroll
  for (int j = 0; j < 8; ++j) {
    const int co = (tcq << 3) + j;
    const float sc = gamma[co] * rsqrtf(var[co] + BN_EPS);
    const float sh = beta[co] - mean[co] * sc;
    float4 v;
    v.x = fmaxf(acc[0][j] * sc + sh, 0.f);
    v.y = fmaxf(acc[1][j] * sc + sh, 0.f);
    v.z = fmaxf(acc[2][j] * sc + sh, 0.f);
    v.w = fmaxf(acc[3][j] * sc + sh, 0.f);
    *(float4*)&xbn[((size_t)(n * C2 + co)) * HWSZ + hw0 + (tmq << 2)] = v;
  }
}

// ---------------------------------------------------------------------------
// K3: conv3x3 pad1: xbn(fp32) [8][256][64][64] -> flow [8][4][64][64] (fp32)
// ---------------------------------------------------------------------------
__global__ __launch_bounds__(256) void k3_conv3(
    const float* __restrict__ xbn, const float* __restrict__ wcc2,
    float* __restrict__ flow) {
  __shared__ float wsm[4 * 2304];
  __shared__ float part[4][4][64];
  const int tid = threadIdx.x;
  const int n = blockIdx.x >> 6;
  const int h = blockIdx.x & 63;
  const int w = tid & 63;
  const int q = tid >> 6;

  for (int idx = tid; idx < 9216; idx += 256) wsm[idx] = wcc2[idx];
  __syncthreads();

  float acc[4] = {0.f, 0.f, 0.f, 0.f};
  for (int ci = q * 64; ci < q * 64 + 64; ++ci) {
    const float* src = xbn + ((size_t)(n * C2 + ci)) * HWSZ;
    const float* wrow = wsm + ci * 9;
#pragma unroll
    for (int dy = 0; dy < 3; ++dy) {
      const int y = h + dy - 1;
      if ((unsigned)y >= 64u) continue;
#pragma unroll
      for (int dx = 0; dx < 3; ++dx) {
        const int x = w + dx - 1;
        const float v = ((unsigned)x < 64u) ? src[y * 64 + x] : 0.f;
#pragma unroll
        for (int f = 0; f < 4; ++f)
          acc[f] = fmaf(v, wrow[f * 2304 + dy * 3 + dx], acc[f]);
      }
    }
  }
#pragma unroll
  for (int f = 0; f < 4; ++f) part[q][f][w] = acc[f];
  __syncthreads();
  {
    const int f = tid >> 6;
    const int ww = tid & 63;
    const float s = part[0][f][ww] + part[1][f][ww] + part[2][f][ww] + part[3][f][ww];
    flow[((size_t)(n * 4 + f)) * HWSZ + h * 64 + ww] = s;
  }
}

// ---------------------------------------------------------------------------
// K4: dual grid_sample (align_corners=True, zeros) + add -> fp32 out
// ix = w + fx, iy = h + fy (exact for these shapes)
// ---------------------------------------------------------------------------
__global__ __launch_bounds__(256) void k4_sample(
    const bf16* __restrict__ x1c, const float* __restrict__ x2,
    const float* __restrict__ flow, float* __restrict__ out) {
  const int n = blockIdx.x >> 6;
  const int h = blockIdx.x & 63;
  const int w = threadIdx.x & 63;
  const int cs = threadIdx.x >> 6;

  const size_t fbase = ((size_t)n * 4) * HWSZ + h * 64 + w;
  const float fx1 = flow[fbase];
  const float fy1 = flow[fbase + HWSZ];
  const float fx2 = flow[fbase + 2 * HWSZ];
  const float fy2 = flow[fbase + 3 * HWSZ];

  int oA1, oB1, oC1, oD1; float wa1, wb1, wc1, wd1;
  {
    const float ix = (float)w + fx1, iy = (float)h + fy1;
    const float x0f = floorf(ix), y0f = floorf(iy);
    const float fx = ix - x0f, fy = iy - y0f;
    const int x0 = (int)x0f, y0 = (int)y0f, x1i = x0 + 1, y1i = y0 + 1;
    const float vx0 = (x0 >= 0 && x0 < 64) ? 1.f : 0.f;
    const float vx1 = (x1i >= 0 && x1i < 64) ? 1.f : 0.f;
    const float vy0 = (y0 >= 0 && y0 < 64) ? 1.f : 0.f;
    const float vy1 = (y1i >= 0 && y1i < 64) ? 1.f : 0.f;
    const int cx0 = min(max(x0, 0), 63), cx1 = min(max(x1i, 0), 63);
    const int cy0 = min(max(y0, 0), 63), cy1 = min(max(y1i, 0), 63);
    oA1 = cy0 * 64 + cx0; oB1 = cy0 * 64 + cx1;
    oC1 = cy1 * 64 + cx0; oD1 = cy1 * 64 + cx1;
    wa1 = (1.f - fx) * (1.f - fy) * vx0 * vy0;
    wb1 = fx * (1.f - fy) * vx1 * vy0;
    wc1 = (1.f - fx) * fy * vx0 * vy1;
    wd1 = fx * fy * vx1 * vy1;
  }
  int oA2, oB2, oC2, oD2; float wa2, wb2, wc2, wd2;
  {
    const float ix = (float)w + fx2, iy = (float)h + fy2;
    const float x0f = floorf(ix), y0f = floorf(iy);
    const float fx = ix - x0f, fy = iy - y0f;
    const int x0 = (int)x0f, y0 = (int)y0f, x1i = x0 + 1, y1i = y0 + 1;
    const float vx0 = (x0 >= 0 && x0 < 64) ? 1.f : 0.f;
    const float vx1 = (x1i >= 0 && x1i < 64) ? 1.f : 0.f;
    const float vy0 = (y0 >= 0 && y0 < 64) ? 1.f : 0.f;
    const float vy1 = (y1i >= 0 && y1i < 64) ? 1.f : 0.f;
    const int cx0 = min(max(x0, 0), 63), cx1 = min(max(x1i, 0), 63);
    const int cy0 = min(max(y0, 0), 63), cy1 = min(max(y1i, 0), 63);
    oA2 = cy0 * 64 + cx0; oB2 = cy0 * 64 + cx1;
    oC2 = cy1 * 64 + cx0; oD2 = cy1 * 64 + cx1;
    wa2 = (1.f - fx) * (1.f - fy) * vx0 * vy0;
    wb2 = fx * (1.f - fy) * vx1 * vy0;
    wc2 = (1.f - fx) * fy * vx0 * vy1;
    wd2 = fx * fy * vx1 * vy1;
  }

  const bf16*  p1 = x1c + ((size_t)n * C2) * HWSZ;
  const float* p2 = x2 + ((size_t)n * C2) * HWSZ;
  const size_t obase = ((size_t)n * C2) * HWSZ + h * 64 + w;
#pragma unroll 4
  for (int i = 0; i < 64; ++i) {
    const int co = (cs << 6) + i;
    const bf16*  q1 = p1 + (size_t)co * HWSZ;
    const float* q2 = p2 + (size_t)co * HWSZ;
    const float u = b2f(q1[oA1]) * wa1 + b2f(q1[oB1]) * wb1 + b2f(q1[oC1]) * wc1 + b2f(q1[oD1]) * wd1
                  + q2[oA2] * wa2 + q2[oB2] * wb2 + q2[oC2] * wc2 + q2[oD2] * wd2;
    out[obase + (size_t)co * HWSZ] = u;
  }
}

// ---------------------------------------------------------------------------
extern "C" void kernel_launch(void* const* d_in, const int* in_sizes, int n_in,
                              void* d_out, int out_size, void* d_ws, size_t ws_size,
                              hipStream_t stream) {
  const float* x1      = (const float*)d_in[0];
  const float* x2      = (const float*)d_in[1];
  const float* w_change= (const float*)d_in[2];
  const float* b_change= (const float*)d_in[3];
  const float* w_cc1   = (const float*)d_in[4];
  const float* bn_gamma= (const float*)d_in[5];
  const float* bn_beta = (const float*)d_in[6];
  const float* bn_mean = (const float*)d_in[7];
  const float* bn_var  = (const float*)d_in[8];
  const float* w_cc2   = (const float*)d_in[9];
  float* out = (float*)d_out;   // reference output dtype is float32

  // workspace layout (~17.5 MiB):
  //   x1c  : bf16, 8*256*4096 = 8388608 elems = 16 MiB
  //   flow : fp32, 131072 elems
  //   wchT : fp32, 131072 elems
  //   wcc1T: fp32, 131072 elems
  bf16*  x1c   = (bf16*)d_ws;
  float* flow  = (float*)((char*)d_ws + 8388608 * sizeof(bf16));
  float* wchT  = flow + 131072;
  float* wcc1T = wchT + 131072;

  // xbn lives in d_out (fp32, same element count), overwritten by K4 afterwards
  float* xbn = out;

  k0_transpose<<<1024, 256, 0, stream>>>(w_change, w_cc1, wchT, wcc1T);
  k1_pool_conv<<<1024, 256, 0, stream>>>(x1, wchT, b_change, x1c);
  k2_cc1_bn_relu<<<1024, 256, 0, stream>>>(x1c, x2, wcc1T, bn_gamma, bn_beta,
                                           bn_mean, bn_var, xbn);
  k3_conv3<<<512, 256, 0, stream>>>(xbn, w_cc2, flow);
  k4_sample<<<512, 256, 0, stream>>>(x1c, x2, flow, out);
}

// Round 4
// 217.943 us; speedup vs baseline: 1.7824x; 1.7824x over previous
//
#include <hip/hip_runtime.h>
#include <hip/hip_bf16.h>

#define NB 8
#define C1 512
#define C2 256
#define HWSZ 4096
#define BN_EPS 1e-5f

typedef __hip_bfloat16 bf16;
typedef __hip_bfloat162 bf162;
typedef __attribute__((ext_vector_type(8))) short short8v;
typedef __attribute__((ext_vector_type(4))) float f32x4;

static __device__ inline float b2f(bf16 h) { return __bfloat162float(h); }

static __device__ inline unsigned short f2bf(float f) {
  union { bf16 h; unsigned short u; } c;
  c.h = __float2bfloat16(f);
  return c.u;
}

// pack 4 floats -> 4 bf16 (8 bytes)
static __device__ inline uint2 pack4(float a, float b, float c, float d) {
  union { uint2 u; bf162 h[2]; } pk;
  pk.h[0] = __float22bfloat162_rn(make_float2(a, b));
  pk.h[1] = __float22bfloat162_rn(make_float2(c, d));
  return pk.u;
}

// ---------------------------------------------------------------------------
// K0: swizzle weights into MFMA B-fragment order (bf16).
// wB[((kstep*16 + ntile)*64 + lane)*8 + i] = W[ci][co],
//   ci = kstep*32 + (lane>>4)*8 + i, co = ntile*16 + (lane&15).
// Source layout: w[co][ci] (OIHW 1x1 => [co][ci]).
// ---------------------------------------------------------------------------
__global__ __launch_bounds__(256) void k0_swizzle(
    const float* __restrict__ wch, const float* __restrict__ wcc1,
    unsigned short* __restrict__ wchB, unsigned short* __restrict__ wcc1B) {
  const int t = blockIdx.x * 256 + threadIdx.x;   // 0 .. 262143
  const int which = t >> 17;
  const int r = t & 131071;
  const int i = r & 7;
  const int lane = (r >> 3) & 63;
  const int ntile = (r >> 9) & 15;
  const int kstep = r >> 13;                      // 0..15
  const int ci = kstep * 32 + (lane >> 4) * 8 + i;
  const int co = ntile * 16 + (lane & 15);
  const float* s = which ? wcc1 : wch;
  unsigned short* d = which ? wcc1B : wchB;
  d[r] = f2bf(s[co * 512 + ci]);
}

// ---------------------------------------------------------------------------
// K1: fused maxpool2x2 + conv1x1 (+bias) via bf16 MFMA.
// GEMM: M=32768 (n*4096+hw), N=256 (co), K=512 (ci). Block tile 32x256, BK=32.
// 4 waves; wave w covers co [w*64, w*64+64) as 4 n-tiles of 16.
// ---------------------------------------------------------------------------
__global__ __launch_bounds__(256) void k1_pool_conv(
    const float* __restrict__ x1, const unsigned short* __restrict__ wB,
    const float* __restrict__ bch, bf16* __restrict__ x1c) {
  __shared__ unsigned short As[32 * 40];   // [m][k] pitch 40 ushorts (80 B)
  const int tid = threadIdx.x;
  const int lane = tid & 63;
  const int wv = tid >> 6;
  const int lrow = lane & 15;
  const int lgrp = lane >> 4;
  const int sm = tid & 31;       // staged m
  const int skq = tid >> 5;      // staged k-quad (0..7)

  const int m0g = blockIdx.x * 32;
  const int n = m0g >> 12;
  const int hw0 = m0g & 4095;
  const int h = hw0 >> 6;
  const int w0 = hw0 & 63;

  f32x4 acc[2][4];
#pragma unroll
  for (int mt = 0; mt < 2; ++mt)
#pragma unroll
    for (int nt = 0; nt < 4; ++nt) acc[mt][nt] = (f32x4){0.f, 0.f, 0.f, 0.f};

  const size_t x1base = ((size_t)n * C1 * 16384) + (size_t)(2 * h) * 128 + (size_t)(2 * (w0 + sm));

  for (int ks = 0; ks < 16; ++ks) {
    const int k0 = ks * 32;
    // ---- stage A: pool 4 channels' 2x2 windows -> 4 bf16
    float av[4];
#pragma unroll
    for (int j = 0; j < 4; ++j) {
      const size_t cioff = (size_t)(k0 + skq * 4 + j) * 16384;
      const float2 a0 = *(const float2*)(x1 + x1base + cioff);
      const float2 a1 = *(const float2*)(x1 + x1base + cioff + 128);
      av[j] = fmaxf(fmaxf(a0.x, a0.y), fmaxf(a1.x, a1.y));
    }
    __syncthreads();   // previous iteration's LDS reads complete
    *(uint2*)&As[sm * 40 + skq * 4] = pack4(av[0], av[1], av[2], av[3]);
    __syncthreads();

    // ---- A fragments (m-tiles 0,16)
    const short8v a0 = *(const short8v*)&As[lrow * 40 + lgrp * 8];
    const short8v a1 = *(const short8v*)&As[(16 + lrow) * 40 + lgrp * 8];

    // ---- B fragments straight from L2 + MFMA
#pragma unroll
    for (int nt = 0; nt < 4; ++nt) {
      const int ntile = wv * 4 + nt;
      const short8v b = *(const short8v*)&wB[(size_t)((ks * 16 + ntile) * 64 + lane) * 8];
      acc[0][nt] = __builtin_amdgcn_mfma_f32_16x16x32_bf16(a0, b, acc[0][nt], 0, 0, 0);
      acc[1][nt] = __builtin_amdgcn_mfma_f32_16x16x32_bf16(a1, b, acc[1][nt], 0, 0, 0);
    }
  }

  // ---- epilogue: +bias, store bf16. D: row=(lane>>4)*4+i, col=lane&15.
#pragma unroll
  for (int nt = 0; nt < 4; ++nt) {
    const int co = wv * 64 + nt * 16 + lrow;
    const float bias = bch[co];
#pragma unroll
    for (int mt = 0; mt < 2; ++mt) {
      const f32x4 v = acc[mt][nt];
      *(uint2*)&x1c[((size_t)(n * C2 + co)) * HWSZ + hw0 + mt * 16 + lgrp * 4] =
          pack4(v.x + bias, v.y + bias, v.z + bias, v.w + bias);
    }
  }
}

// ---------------------------------------------------------------------------
// K2: fused concat(x1c,x2) + conv1x1 + BN + ReLU via bf16 MFMA -> xbn (fp32, d_out)
// ---------------------------------------------------------------------------
__global__ __launch_bounds__(256) void k2_cc1_bn_relu(
    const bf16* __restrict__ x1c, const float* __restrict__ x2,
    const unsigned short* __restrict__ wB,
    const float* __restrict__ gamma, const float* __restrict__ beta,
    const float* __restrict__ mean, const float* __restrict__ var,
    float* __restrict__ xbn) {
  __shared__ unsigned short As[32 * 40];
  const int tid = threadIdx.x;
  const int lane = tid & 63;
  const int wv = tid >> 6;
  const int lrow = lane & 15;
  const int lgrp = lane >> 4;
  const int sm = tid & 31;
  const int skq = tid >> 5;

  const int m0g = blockIdx.x * 32;
  const int n = m0g >> 12;
  const int hw0 = m0g & 4095;

  const unsigned short* x1cu = (const unsigned short*)x1c;

  f32x4 acc[2][4];
#pragma unroll
  for (int mt = 0; mt < 2; ++mt)
#pragma unroll
    for (int nt = 0; nt < 4; ++nt) acc[mt][nt] = (f32x4){0.f, 0.f, 0.f, 0.f};

  for (int ks = 0; ks < 16; ++ks) {
    const int k0 = ks * 32;
    unsigned short pk[4];
#pragma unroll
    for (int j = 0; j < 4; ++j) {
      const int ci = k0 + skq * 4 + j;
      if (ci < 256) {
        pk[j] = x1cu[((size_t)(n * C2 + ci)) * HWSZ + hw0 + sm];   // already bf16
      } else {
        pk[j] = f2bf(x2[((size_t)(n * C2 + (ci - 256))) * HWSZ + hw0 + sm]);
      }
    }
    __syncthreads();
    {
      uint2 u;
      u.x = (unsigned)pk[0] | ((unsigned)pk[1] << 16);
      u.y = (unsigned)pk[2] | ((unsigned)pk[3] << 16);
      *(uint2*)&As[sm * 40 + skq * 4] = u;
    }
    __syncthreads();

    const short8v a0 = *(const short8v*)&As[lrow * 40 + lgrp * 8];
    const short8v a1 = *(const short8v*)&As[(16 + lrow) * 40 + lgrp * 8];

#pragma unroll
    for (int nt = 0; nt < 4; ++nt) {
      const int ntile = wv * 4 + nt;
      const short8v b = *(const short8v*)&wB[(size_t)((ks * 16 + ntile) * 64 + lane) * 8];
      acc[0][nt] = __builtin_amdgcn_mfma_f32_16x16x32_bf16(a0, b, acc[0][nt], 0, 0, 0);
      acc[1][nt] = __builtin_amdgcn_mfma_f32_16x16x32_bf16(a1, b, acc[1][nt], 0, 0, 0);
    }
  }

  // ---- epilogue: BN + ReLU, store fp32
#pragma unroll
  for (int nt = 0; nt < 4; ++nt) {
    const int co = wv * 64 + nt * 16 + lrow;
    const float sc = gamma[co] * rsqrtf(var[co] + BN_EPS);
    const float sh = beta[co] - mean[co] * sc;
#pragma unroll
    for (int mt = 0; mt < 2; ++mt) {
      const f32x4 vv = acc[mt][nt];
      float4 v;
      v.x = fmaxf(vv.x * sc + sh, 0.f);
      v.y = fmaxf(vv.y * sc + sh, 0.f);
      v.z = fmaxf(vv.z * sc + sh, 0.f);
      v.w = fmaxf(vv.w * sc + sh, 0.f);
      *(float4*)&xbn[((size_t)(n * C2 + co)) * HWSZ + hw0 + mt * 16 + lgrp * 4] = v;
    }
  }
}

// ---------------------------------------------------------------------------
// K3: conv3x3 pad1: xbn(fp32) [8][256][64][64] -> flow [8][4][64][64] (fp32)
// ---------------------------------------------------------------------------
__global__ __launch_bounds__(256) void k3_conv3(
    const float* __restrict__ xbn, const float* __restrict__ wcc2,
    float* __restrict__ flow) {
  __shared__ float wsm[4 * 2304];
  __shared__ float part[4][4][64];
  const int tid = threadIdx.x;
  const int n = blockIdx.x >> 6;
  const int h = blockIdx.x & 63;
  const int w = tid & 63;
  const int q = tid >> 6;

  for (int idx = tid; idx < 9216; idx += 256) wsm[idx] = wcc2[idx];
  __syncthreads();

  float acc[4] = {0.f, 0.f, 0.f, 0.f};
  for (int ci = q * 64; ci < q * 64 + 64; ++ci) {
    const float* src = xbn + ((size_t)(n * C2 + ci)) * HWSZ;
    const float* wrow = wsm + ci * 9;
#pragma unroll
    for (int dy = 0; dy < 3; ++dy) {
      const int y = h + dy - 1;
      if ((unsigned)y >= 64u) continue;
#pragma unroll
      for (int dx = 0; dx < 3; ++dx) {
        const int x = w + dx - 1;
        const float v = ((unsigned)x < 64u) ? src[y * 64 + x] : 0.f;
#pragma unroll
        for (int f = 0; f < 4; ++f)
          acc[f] = fmaf(v, wrow[f * 2304 + dy * 3 + dx], acc[f]);
      }
    }
  }
#pragma unroll
  for (int f = 0; f < 4; ++f) part[q][f][w] = acc[f];
  __syncthreads();
  {
    const int f = tid >> 6;
    const int ww = tid & 63;
    const float s = part[0][f][ww] + part[1][f][ww] + part[2][f][ww] + part[3][f][ww];
    flow[((size_t)(n * 4 + f)) * HWSZ + h * 64 + ww] = s;
  }
}

// ---------------------------------------------------------------------------
// K4: dual grid_sample (align_corners=True, zeros) + add -> fp32 out
// ix = w + fx, iy = h + fy (exact for these shapes)
// ---------------------------------------------------------------------------
__global__ __launch_bounds__(256) void k4_sample(
    const bf16* __restrict__ x1c, const float* __restrict__ x2,
    const float* __restrict__ flow, float* __restrict__ out) {
  const int n = blockIdx.x >> 6;
  const int h = blockIdx.x & 63;
  const int w = threadIdx.x & 63;
  const int cs = threadIdx.x >> 6;

  const size_t fbase = ((size_t)n * 4) * HWSZ + h * 64 + w;
  const float fx1 = flow[fbase];
  const float fy1 = flow[fbase + HWSZ];
  const float fx2 = flow[fbase + 2 * HWSZ];
  const float fy2 = flow[fbase + 3 * HWSZ];

  int oA1, oB1, oC1, oD1; float wa1, wb1, wc1, wd1;
  {
    const float ix = (float)w + fx1, iy = (float)h + fy1;
    const float x0f = floorf(ix), y0f = floorf(iy);
    const float fx = ix - x0f, fy = iy - y0f;
    const int x0 = (int)x0f, y0 = (int)y0f, x1i = x0 + 1, y1i = y0 + 1;
    const float vx0 = (x0 >= 0 && x0 < 64) ? 1.f : 0.f;
    const float vx1 = (x1i >= 0 && x1i < 64) ? 1.f : 0.f;
    const float vy0 = (y0 >= 0 && y0 < 64) ? 1.f : 0.f;
    const float vy1 = (y1i >= 0 && y1i < 64) ? 1.f : 0.f;
    const int cx0 = min(max(x0, 0), 63), cx1 = min(max(x1i, 0), 63);
    const int cy0 = min(max(y0, 0), 63), cy1 = min(max(y1i, 0), 63);
    oA1 = cy0 * 64 + cx0; oB1 = cy0 * 64 + cx1;
    oC1 = cy1 * 64 + cx0; oD1 = cy1 * 64 + cx1;
    wa1 = (1.f - fx) * (1.f - fy) * vx0 * vy0;
    wb1 = fx * (1.f - fy) * vx1 * vy0;
    wc1 = (1.f - fx) * fy * vx0 * vy1;
    wd1 = fx * fy * vx1 * vy1;
  }
  int oA2, oB2, oC2, oD2; float wa2, wb2, wc2, wd2;
  {
    const float ix = (float)w + fx2, iy = (float)h + fy2;
    const float x0f = floorf(ix), y0f = floorf(iy);
    const float fx = ix - x0f, fy = iy - y0f;
    const int x0 = (int)x0f, y0 = (int)y0f, x1i = x0 + 1, y1i = y0 + 1;
    const float vx0 = (x0 >= 0 && x0 < 64) ? 1.f : 0.f;
    const float vx1 = (x1i >= 0 && x1i < 64) ? 1.f : 0.f;
    const float vy0 = (y0 >= 0 && y0 < 64) ? 1.f : 0.f;
    const float vy1 = (y1i >= 0 && y1i < 64) ? 1.f : 0.f;
    const int cx0 = min(max(x0, 0), 63), cx1 = min(max(x1i, 0), 63);
    const int cy0 = min(max(y0, 0), 63), cy1 = min(max(y1i, 0), 63);
    oA2 = cy0 * 64 + cx0; oB2 = cy0 * 64 + cx1;
    oC2 = cy1 * 64 + cx0; oD2 = cy1 * 64 + cx1;
    wa2 = (1.f - fx) * (1.f - fy) * vx0 * vy0;
    wb2 = fx * (1.f - fy) * vx1 * vy0;
    wc2 = (1.f - fx) * fy * vx0 * vy1;
    wd2 = fx * fy * vx1 * vy1;
  }

  const bf16*  p1 = x1c + ((size_t)n * C2) * HWSZ;
  const float* p2 = x2 + ((size_t)n * C2) * HWSZ;
  const size_t obase = ((size_t)n * C2) * HWSZ + h * 64 + w;
#pragma unroll 4
  for (int i = 0; i < 64; ++i) {
    const int co = (cs << 6) + i;
    const bf16*  q1 = p1 + (size_t)co * HWSZ;
    const float* q2 = p2 + (size_t)co * HWSZ;
    const float u = b2f(q1[oA1]) * wa1 + b2f(q1[oB1]) * wb1 + b2f(q1[oC1]) * wc1 + b2f(q1[oD1]) * wd1
                  + q2[oA2] * wa2 + q2[oB2] * wb2 + q2[oC2] * wc2 + q2[oD2] * wd2;
    out[obase + (size_t)co * HWSZ] = u;
  }
}

// ---------------------------------------------------------------------------
extern "C" void kernel_launch(void* const* d_in, const int* in_sizes, int n_in,
                              void* d_out, int out_size, void* d_ws, size_t ws_size,
                              hipStream_t stream) {
  const float* x1      = (const float*)d_in[0];
  const float* x2      = (const float*)d_in[1];
  const float* w_change= (const float*)d_in[2];
  const float* b_change= (const float*)d_in[3];
  const float* w_cc1   = (const float*)d_in[4];
  const float* bn_gamma= (const float*)d_in[5];
  const float* bn_beta = (const float*)d_in[6];
  const float* bn_mean = (const float*)d_in[7];
  const float* bn_var  = (const float*)d_in[8];
  const float* w_cc2   = (const float*)d_in[9];
  float* out = (float*)d_out;   // reference output dtype is float32

  // workspace layout (~17.8 MiB):
  //   x1c  : bf16, 8388608 elems (16 MiB)          @ 0
  //   flow : fp32, 131072 elems (512 KiB)          @ 16777216
  //   wchB : bf16 swizzled, 131072 elems (256 KiB) @ 17301504
  //   wcc1B: bf16 swizzled, 131072 elems (256 KiB) @ 17563648
  bf16*           x1c   = (bf16*)d_ws;
  float*          flow  = (float*)((char*)d_ws + 16777216);
  unsigned short* wchB  = (unsigned short*)((char*)d_ws + 17301504);
  unsigned short* wcc1B = (unsigned short*)((char*)d_ws + 17563648);

  float* xbn = out;   // xbn (fp32) lives in d_out, overwritten by K4

  k0_swizzle<<<1024, 256, 0, stream>>>(w_change, w_cc1, wchB, wcc1B);
  k1_pool_conv<<<1024, 256, 0, stream>>>(x1, wchB, b_change, x1c);
  k2_cc1_bn_relu<<<1024, 256, 0, stream>>>(x1c, x2, wcc1B, bn_gamma, bn_beta,
                                           bn_mean, bn_var, xbn);
  k3_conv3<<<512, 256, 0, stream>>>(xbn, w_cc2, flow);
  k4_sample<<<512, 256, 0, stream>>>(x1c, x2, flow, out);
}

// Round 5
// 206.359 us; speedup vs baseline: 1.8825x; 1.0561x over previous
//
#include <hip/hip_runtime.h>
#include <hip/hip_bf16.h>

#define NB 8
#define C1 512
#define C2 256
#define HWSZ 4096
#define BN_EPS 1e-5f

typedef __hip_bfloat16 bf16;
typedef __hip_bfloat162 bf162;
typedef __attribute__((ext_vector_type(8))) short short8v;
typedef __attribute__((ext_vector_type(4))) float f32x4;

static __device__ inline float b2f(bf16 h) { return __bfloat162float(h); }

static __device__ inline unsigned short f2bf(float f) {
  union { bf16 h; unsigned short u; } c;
  c.h = __float2bfloat16(f);
  return c.u;
}

// pack 4 floats -> 4 bf16 (8 bytes)
static __device__ inline uint2 pack4(float a, float b, float c, float d) {
  union { uint2 u; bf162 h[2]; } pk;
  pk.h[0] = __float22bfloat162_rn(make_float2(a, b));
  pk.h[1] = __float22bfloat162_rn(make_float2(c, d));
  return pk.u;
}

// ---------------------------------------------------------------------------
// K0: swizzle weights into MFMA B-fragment order (bf16).
// wB[((kstep*16 + ntile)*64 + lane)*8 + i] = W[ci][co],
//   ci = kstep*32 + (lane>>4)*8 + i, co = ntile*16 + (lane&15).
// ---------------------------------------------------------------------------
__global__ __launch_bounds__(256) void k0_swizzle(
    const float* __restrict__ wch, const float* __restrict__ wcc1,
    unsigned short* __restrict__ wchB, unsigned short* __restrict__ wcc1B) {
  const int t = blockIdx.x * 256 + threadIdx.x;   // 0 .. 262143
  const int which = t >> 17;
  const int r = t & 131071;
  const int i = r & 7;
  const int lane = (r >> 3) & 63;
  const int ntile = (r >> 9) & 15;
  const int kstep = r >> 13;                      // 0..15
  const int ci = kstep * 32 + (lane >> 4) * 8 + i;
  const int co = ntile * 16 + (lane & 15);
  const float* s = which ? wcc1 : wch;
  unsigned short* d = which ? wcc1B : wchB;
  d[r] = f2bf(s[co * 512 + ci]);
}

// ---------------------------------------------------------------------------
// K1: fused maxpool2x2 + conv1x1 (+bias) via bf16 MFMA, register-prefetched.
// Block tile 32(m) x 256(co), K=512, BK=32. 4 waves.
// ---------------------------------------------------------------------------
__global__ __launch_bounds__(256) void k1_pool_conv(
    const float* __restrict__ x1, const unsigned short* __restrict__ wB,
    const float* __restrict__ bch, bf16* __restrict__ x1c) {
  __shared__ unsigned short As[32 * 40];   // [m][k] pitch 40 ushorts (80 B)
  const int tid = threadIdx.x;
  const int lane = tid & 63;
  const int wv = tid >> 6;
  const int lrow = lane & 15;
  const int lgrp = lane >> 4;
  const int sm = tid & 31;       // staged m
  const int skq = tid >> 5;      // staged k-quad (0..7)

  const int m0g = blockIdx.x * 32;
  const int n = m0g >> 12;
  const int hw0 = m0g & 4095;
  const int h = hw0 >> 6;
  const int w0 = hw0 & 63;

  f32x4 acc[2][4];
#pragma unroll
  for (int mt = 0; mt < 2; ++mt)
#pragma unroll
    for (int nt = 0; nt < 4; ++nt) acc[mt][nt] = (f32x4){0.f, 0.f, 0.f, 0.f};

  const size_t x1base = ((size_t)n * C1 * 16384) + (size_t)(2 * h) * 128 + (size_t)(2 * (w0 + sm));

  // prefetch ks=0 pooled values into registers
  float av[4];
#pragma unroll
  for (int j = 0; j < 4; ++j) {
    const size_t cioff = (size_t)(skq * 4 + j) * 16384;
    const float2 p0 = *(const float2*)(x1 + x1base + cioff);
    const float2 p1 = *(const float2*)(x1 + x1base + cioff + 128);
    av[j] = fmaxf(fmaxf(p0.x, p0.y), fmaxf(p1.x, p1.y));
  }

  for (int ks = 0; ks < 16; ++ks) {
    __syncthreads();   // previous iteration's LDS frag reads complete
    *(uint2*)&As[sm * 40 + skq * 4] = pack4(av[0], av[1], av[2], av[3]);
    __syncthreads();

    const short8v a0 = *(const short8v*)&As[lrow * 40 + lgrp * 8];
    const short8v a1 = *(const short8v*)&As[(16 + lrow) * 40 + lgrp * 8];

    // issue next K-step's global loads BEFORE the MFMAs (latency hides under them)
    if (ks < 15) {
      const int k0 = (ks + 1) * 32;
#pragma unroll
      for (int j = 0; j < 4; ++j) {
        const size_t cioff = (size_t)(k0 + skq * 4 + j) * 16384;
        const float2 p0 = *(const float2*)(x1 + x1base + cioff);
        const float2 p1 = *(const float2*)(x1 + x1base + cioff + 128);
        av[j] = fmaxf(fmaxf(p0.x, p0.y), fmaxf(p1.x, p1.y));
      }
    }

#pragma unroll
    for (int nt = 0; nt < 4; ++nt) {
      const int ntile = wv * 4 + nt;
      const short8v b = *(const short8v*)&wB[(size_t)((ks * 16 + ntile) * 64 + lane) * 8];
      acc[0][nt] = __builtin_amdgcn_mfma_f32_16x16x32_bf16(a0, b, acc[0][nt], 0, 0, 0);
      acc[1][nt] = __builtin_amdgcn_mfma_f32_16x16x32_bf16(a1, b, acc[1][nt], 0, 0, 0);
    }
  }

  // ---- epilogue: +bias, store bf16. D: row=(lane>>4)*4+i, col=lane&15.
#pragma unroll
  for (int nt = 0; nt < 4; ++nt) {
    const int co = wv * 64 + nt * 16 + lrow;
    const float bias = bch[co];
#pragma unroll
    for (int mt = 0; mt < 2; ++mt) {
      const f32x4 v = acc[mt][nt];
      *(uint2*)&x1c[((size_t)(n * C2 + co)) * HWSZ + hw0 + mt * 16 + lgrp * 4] =
          pack4(v.x + bias, v.y + bias, v.z + bias, v.w + bias);
    }
  }
}

// ---------------------------------------------------------------------------
// K2: fused concat(x1c,x2) + conv1x1 + BN + ReLU via bf16 MFMA -> xbn (fp32, d_out)
// Vectorized staging: thread stages 4 contiguous hw of one channel.
// ks<8 reads x1c (uint2 of 4 bf16), ks>=8 reads x2 (float4) — uniform branch.
// ---------------------------------------------------------------------------
__global__ __launch_bounds__(256) void k2_cc1_bn_relu(
    const bf16* __restrict__ x1c, const float* __restrict__ x2,
    const unsigned short* __restrict__ wB,
    const float* __restrict__ gamma, const float* __restrict__ beta,
    const float* __restrict__ mean, const float* __restrict__ var,
    float* __restrict__ xbn) {
  __shared__ unsigned short As[32 * 40];
  const int tid = threadIdx.x;
  const int lane = tid & 63;
  const int wv = tid >> 6;
  const int lrow = lane & 15;
  const int lgrp = lane >> 4;
  const int ch = tid >> 3;        // staged channel-within-BK (0..31)
  const int mq = (tid & 7) * 4;   // staged m-quad base

  const int m0g = blockIdx.x * 32;
  const int n = m0g >> 12;
  const int hw0 = m0g & 4095;

  const unsigned short* x1cu = (const unsigned short*)x1c;

  f32x4 acc[2][4];
#pragma unroll
  for (int mt = 0; mt < 2; ++mt)
#pragma unroll
    for (int nt = 0; nt < 4; ++nt) acc[mt][nt] = (f32x4){0.f, 0.f, 0.f, 0.f};

  uint2 cu;   // current x1c stage (4 bf16)
  float4 cf;  // current x2 stage
  cu = *(const uint2*)&x1cu[((size_t)(n * C2 + ch)) * HWSZ + hw0 + mq];

  for (int ks = 0; ks < 16; ++ks) {
    unsigned short pk[4];
    if (ks < 8) {
      pk[0] = (unsigned short)(cu.x & 0xffffu);
      pk[1] = (unsigned short)(cu.x >> 16);
      pk[2] = (unsigned short)(cu.y & 0xffffu);
      pk[3] = (unsigned short)(cu.y >> 16);
    } else {
      pk[0] = f2bf(cf.x); pk[1] = f2bf(cf.y); pk[2] = f2bf(cf.z); pk[3] = f2bf(cf.w);
    }
    // prefetch next K-step
    const int kn = ks + 1;
    if (kn < 8) {
      cu = *(const uint2*)&x1cu[((size_t)(n * C2 + kn * 32 + ch)) * HWSZ + hw0 + mq];
    } else if (kn < 16) {
      cf = *(const float4*)&x2[((size_t)(n * C2 + (kn - 8) * 32 + ch)) * HWSZ + hw0 + mq];
    }
    __syncthreads();
    As[(mq + 0) * 40 + ch] = pk[0];
    As[(mq + 1) * 40 + ch] = pk[1];
    As[(mq + 2) * 40 + ch] = pk[2];
    As[(mq + 3) * 40 + ch] = pk[3];
    __syncthreads();

    const short8v a0 = *(const short8v*)&As[lrow * 40 + lgrp * 8];
    const short8v a1 = *(const short8v*)&As[(16 + lrow) * 40 + lgrp * 8];

#pragma unroll
    for (int nt = 0; nt < 4; ++nt) {
      const int ntile = wv * 4 + nt;
      const short8v b = *(const short8v*)&wB[(size_t)((ks * 16 + ntile) * 64 + lane) * 8];
      acc[0][nt] = __builtin_amdgcn_mfma_f32_16x16x32_bf16(a0, b, acc[0][nt], 0, 0, 0);
      acc[1][nt] = __builtin_amdgcn_mfma_f32_16x16x32_bf16(a1, b, acc[1][nt], 0, 0, 0);
    }
  }

  // ---- epilogue: BN + ReLU, store fp32
#pragma unroll
  for (int nt = 0; nt < 4; ++nt) {
    const int co = wv * 64 + nt * 16 + lrow;
    const float sc = gamma[co] * rsqrtf(var[co] + BN_EPS);
    const float sh = beta[co] - mean[co] * sc;
#pragma unroll
    for (int mt = 0; mt < 2; ++mt) {
      const f32x4 vv = acc[mt][nt];
      float4 v;
      v.x = fmaxf(vv.x * sc + sh, 0.f);
      v.y = fmaxf(vv.y * sc + sh, 0.f);
      v.z = fmaxf(vv.z * sc + sh, 0.f);
      v.w = fmaxf(vv.w * sc + sh, 0.f);
      *(float4*)&xbn[((size_t)(n * C2 + co)) * HWSZ + hw0 + mt * 16 + lgrp * 4] = v;
    }
  }
}

// ---------------------------------------------------------------------------
// K3: conv3x3 pad1: xbn(fp32) [8][256][64][64] -> flow [8][4][64][64] (fp32)
// ---------------------------------------------------------------------------
__global__ __launch_bounds__(256) void k3_conv3(
    const float* __restrict__ xbn, const float* __restrict__ wcc2,
    float* __restrict__ flow) {
  __shared__ float wsm[4 * 2304];
  __shared__ float part[4][4][64];
  const int tid = threadIdx.x;
  const int n = blockIdx.x >> 6;
  const int h = blockIdx.x & 63;
  const int w = tid & 63;
  const int q = tid >> 6;

  for (int idx = tid; idx < 9216; idx += 256) wsm[idx] = wcc2[idx];
  __syncthreads();

  float acc[4] = {0.f, 0.f, 0.f, 0.f};
  for (int ci = q * 64; ci < q * 64 + 64; ++ci) {
    const float* src = xbn + ((size_t)(n * C2 + ci)) * HWSZ;
    const float* wrow = wsm + ci * 9;
#pragma unroll
    for (int dy = 0; dy < 3; ++dy) {
      const int y = h + dy - 1;
      if ((unsigned)y >= 64u) continue;
#pragma unroll
      for (int dx = 0; dx < 3; ++dx) {
        const int x = w + dx - 1;
        const float v = ((unsigned)x < 64u) ? src[y * 64 + x] : 0.f;
#pragma unroll
        for (int f = 0; f < 4; ++f)
          acc[f] = fmaf(v, wrow[f * 2304 + dy * 3 + dx], acc[f]);
      }
    }
  }
#pragma unroll
  for (int f = 0; f < 4; ++f) part[q][f][w] = acc[f];
  __syncthreads();
  {
    const int f = tid >> 6;
    const int ww = tid & 63;
    const float s = part[0][f][ww] + part[1][f][ww] + part[2][f][ww] + part[3][f][ww];
    flow[((size_t)(n * 4 + f)) * HWSZ + h * 64 + ww] = s;
  }
}

// ---------------------------------------------------------------------------
// K4: dual grid_sample (align_corners=True, zeros) + add -> fp32 out
// 1024-thread blocks: 16 waves/block, 2 blocks/CU -> full occupancy for
// latency hiding of the channel gathers. 16 channels per thread.
// ---------------------------------------------------------------------------
__global__ __launch_bounds__(1024) void k4_sample(
    const bf16* __restrict__ x1c, const float* __restrict__ x2,
    const float* __restrict__ flow, float* __restrict__ out) {
  const int n = blockIdx.x >> 6;
  const int h = blockIdx.x & 63;
  const int w = threadIdx.x & 63;
  const int cs = threadIdx.x >> 6;   // 0..15

  const size_t fbase = ((size_t)n * 4) * HWSZ + h * 64 + w;
  const float fx1 = flow[fbase];
  const float fy1 = flow[fbase + HWSZ];
  const float fx2 = flow[fbase + 2 * HWSZ];
  const float fy2 = flow[fbase + 3 * HWSZ];

  int oA1, oB1, oC1, oD1; float wa1, wb1, wc1, wd1;
  {
    const float ix = (float)w + fx1, iy = (float)h + fy1;
    const float x0f = floorf(ix), y0f = floorf(iy);
    const float fx = ix - x0f, fy = iy - y0f;
    const int x0 = (int)x0f, y0 = (int)y0f, x1i = x0 + 1, y1i = y0 + 1;
    const float vx0 = (x0 >= 0 && x0 < 64) ? 1.f : 0.f;
    const float vx1 = (x1i >= 0 && x1i < 64) ? 1.f : 0.f;
    const float vy0 = (y0 >= 0 && y0 < 64) ? 1.f : 0.f;
    const float vy1 = (y1i >= 0 && y1i < 64) ? 1.f : 0.f;
    const int cx0 = min(max(x0, 0), 63), cx1 = min(max(x1i, 0), 63);
    const int cy0 = min(max(y0, 0), 63), cy1 = min(max(y1i, 0), 63);
    oA1 = cy0 * 64 + cx0; oB1 = cy0 * 64 + cx1;
    oC1 = cy1 * 64 + cx0; oD1 = cy1 * 64 + cx1;
    wa1 = (1.f - fx) * (1.f - fy) * vx0 * vy0;
    wb1 = fx * (1.f - fy) * vx1 * vy0;
    wc1 = (1.f - fx) * fy * vx0 * vy1;
    wd1 = fx * fy * vx1 * vy1;
  }
  int oA2, oB2, oC2, oD2; float wa2, wb2, wc2, wd2;
  {
    const float ix = (float)w + fx2, iy = (float)h + fy2;
    const float x0f = floorf(ix), y0f = floorf(iy);
    const float fx = ix - x0f, fy = iy - y0f;
    const int x0 = (int)x0f, y0 = (int)y0f, x1i = x0 + 1, y1i = y0 + 1;
    const float vx0 = (x0 >= 0 && x0 < 64) ? 1.f : 0.f;
    const float vx1 = (x1i >= 0 && x1i < 64) ? 1.f : 0.f;
    const float vy0 = (y0 >= 0 && y0 < 64) ? 1.f : 0.f;
    const float vy1 = (y1i >= 0 && y1i < 64) ? 1.f : 0.f;
    const int cx0 = min(max(x0, 0), 63), cx1 = min(max(x1i, 0), 63);
    const int cy0 = min(max(y0, 0), 63), cy1 = min(max(y1i, 0), 63);
    oA2 = cy0 * 64 + cx0; oB2 = cy0 * 64 + cx1;
    oC2 = cy1 * 64 + cx0; oD2 = cy1 * 64 + cx1;
    wa2 = (1.f - fx) * (1.f - fy) * vx0 * vy0;
    wb2 = fx * (1.f - fy) * vx1 * vy0;
    wc2 = (1.f - fx) * fy * vx0 * vy1;
    wd2 = fx * fy * vx1 * vy1;
  }

  const bf16*  p1 = x1c + ((size_t)n * C2) * HWSZ;
  const float* p2 = x2 + ((size_t)n * C2) * HWSZ;
  const size_t obase = ((size_t)n * C2) * HWSZ + h * 64 + w;
#pragma unroll 4
  for (int i = 0; i < 16; ++i) {
    const int co = cs * 16 + i;
    const bf16*  q1 = p1 + (size_t)co * HWSZ;
    const float* q2 = p2 + (size_t)co * HWSZ;
    const float u = b2f(q1[oA1]) * wa1 + b2f(q1[oB1]) * wb1 + b2f(q1[oC1]) * wc1 + b2f(q1[oD1]) * wd1
                  + q2[oA2] * wa2 + q2[oB2] * wb2 + q2[oC2] * wc2 + q2[oD2] * wd2;
    out[obase + (size_t)co * HWSZ] = u;
  }
}

// ---------------------------------------------------------------------------
extern "C" void kernel_launch(void* const* d_in, const int* in_sizes, int n_in,
                              void* d_out, int out_size, void* d_ws, size_t ws_size,
                              hipStream_t stream) {
  const float* x1      = (const float*)d_in[0];
  const float* x2      = (const float*)d_in[1];
  const float* w_change= (const float*)d_in[2];
  const float* b_change= (const float*)d_in[3];
  const float* w_cc1   = (const float*)d_in[4];
  const float* bn_gamma= (const float*)d_in[5];
  const float* bn_beta = (const float*)d_in[6];
  const float* bn_mean = (const float*)d_in[7];
  const float* bn_var  = (const float*)d_in[8];
  const float* w_cc2   = (const float*)d_in[9];
  float* out = (float*)d_out;   // reference output dtype is float32

  // workspace layout (~17.8 MiB):
  //   x1c  : bf16, 8388608 elems (16 MiB)          @ 0
  //   flow : fp32, 131072 elems (512 KiB)          @ 16777216
  //   wchB : bf16 swizzled, 131072 elems (256 KiB) @ 17301504
  //   wcc1B: bf16 swizzled, 131072 elems (256 KiB) @ 17563648
  bf16*           x1c   = (bf16*)d_ws;
  float*          flow  = (float*)((char*)d_ws + 16777216);
  unsigned short* wchB  = (unsigned short*)((char*)d_ws + 17301504);
  unsigned short* wcc1B = (unsigned short*)((char*)d_ws + 17563648);

  float* xbn = out;   // xbn (fp32) lives in d_out, overwritten by K4

  k0_swizzle<<<1024, 256, 0, stream>>>(w_change, w_cc1, wchB, wcc1B);
  k1_pool_conv<<<1024, 256, 0, stream>>>(x1, wchB, b_change, x1c);
  k2_cc1_bn_relu<<<1024, 256, 0, stream>>>(x1c, x2, wcc1B, bn_gamma, bn_beta,
                                           bn_mean, bn_var, xbn);
  k3_conv3<<<512, 256, 0, stream>>>(xbn, w_cc2, flow);
  k4_sample<<<512, 1024, 0, stream>>>(x1c, x2, flow, out);
}

// Round 6
// 150.445 us; speedup vs baseline: 2.5821x; 1.3717x over previous
//
#include <hip/hip_runtime.h>
#include <hip/hip_bf16.h>

#define NB 8
#define C1 512
#define C2 256
#define HWSZ 4096
#define BN_EPS 1e-5f
#define P2 264   // As2 pitch in ushorts

typedef __hip_bfloat16 bf16;
typedef __hip_bfloat162 bf162;
typedef __attribute__((ext_vector_type(8))) short short8v;
typedef __attribute__((ext_vector_type(4))) float f32x4;

static __device__ inline float b2f(bf16 h) { return __bfloat162float(h); }

static __device__ inline unsigned short f2bf(float f) {
  union { bf16 h; unsigned short u; } c;
  c.h = __float2bfloat16(f);
  return c.u;
}

static __device__ inline uint2 pack4(float a, float b, float c, float d) {
  union { uint2 u; bf162 h[2]; } pk;
  pk.h[0] = __float22bfloat162_rn(make_float2(a, b));
  pk.h[1] = __float22bfloat162_rn(make_float2(c, d));
  return pk.u;
}

// ---------------------------------------------------------------------------
// K0: swizzle weights into MFMA B-fragment order (bf16).
// wB[((kstep*16 + ntile)*64 + lane)*8 + i] = W[co][ci],
//   ci = kstep*32 + (lane>>4)*8 + i, co = ntile*16 + (lane&15).
// ---------------------------------------------------------------------------
__global__ __launch_bounds__(256) void k0_swizzle(
    const float* __restrict__ wch, const float* __restrict__ wcc1,
    unsigned short* __restrict__ wchB, unsigned short* __restrict__ wcc1B) {
  const int t = blockIdx.x * 256 + threadIdx.x;   // 0 .. 262143
  const int which = t >> 17;
  const int r = t & 131071;
  const int i = r & 7;
  const int lane = (r >> 3) & 63;
  const int ntile = (r >> 9) & 15;
  const int kstep = r >> 13;                      // 0..15
  const int ci = kstep * 32 + (lane >> 4) * 8 + i;
  const int co = ntile * 16 + (lane & 15);
  const float* s = which ? wcc1 : wch;
  unsigned short* d = which ? wcc1B : wchB;
  d[r] = f2bf(s[co * 512 + ci]);
}

// ---------------------------------------------------------------------------
// K12: fused [maxpool2x2 + conv1x1 + bias] -> x1c, then
//            [concat + conv1x1 + BN + ReLU] -> xbn (bf16)
// Phase A output tile kept in LDS (As2) = phase B's A-operand for ci<256.
// Block tile 32(m=hw) x 256(co); 256 threads, 4 waves.
// ---------------------------------------------------------------------------
__global__ __launch_bounds__(256) void k12_fused(
    const float* __restrict__ x1, const float* __restrict__ x2,
    const unsigned short* __restrict__ wchB, const unsigned short* __restrict__ wcc1B,
    const float* __restrict__ bch,
    const float* __restrict__ gamma, const float* __restrict__ beta,
    const float* __restrict__ mean, const float* __restrict__ var,
    bf16* __restrict__ x1c, bf16* __restrict__ xbn) {
  __shared__ unsigned short As[32 * 40];     // staging tile (phase A: pooled x1; phase B: x2)
  __shared__ unsigned short As2[32 * P2];    // phase A output = phase B A-operand (ci<256)
  const int tid = threadIdx.x;
  const int lane = tid & 63;
  const int wv = tid >> 6;
  const int lrow = lane & 15;
  const int lgrp = lane >> 4;
  const int sm = tid & 31;       // phase A staged m
  const int skq = tid >> 5;      // phase A staged k-quad (0..7)

  const int m0g = blockIdx.x * 32;
  const int n = m0g >> 12;
  const int hw0 = m0g & 4095;
  const int h = hw0 >> 6;
  const int w0 = hw0 & 63;

  f32x4 acc[2][4];
#pragma unroll
  for (int mt = 0; mt < 2; ++mt)
#pragma unroll
    for (int nt = 0; nt < 4; ++nt) acc[mt][nt] = (f32x4){0.f, 0.f, 0.f, 0.f};

  // ================= phase A: maxpool + conv1x1(w_change) =================
  const size_t x1base = ((size_t)n * C1 * 16384) + (size_t)(2 * h) * 128 + (size_t)(2 * (w0 + sm));

  float av[4];
#pragma unroll
  for (int j = 0; j < 4; ++j) {
    const size_t cioff = (size_t)(skq * 4 + j) * 16384;
    const float2 p0 = *(const float2*)(x1 + x1base + cioff);
    const float2 p1 = *(const float2*)(x1 + x1base + cioff + 128);
    av[j] = fmaxf(fmaxf(p0.x, p0.y), fmaxf(p1.x, p1.y));
  }

  for (int ks = 0; ks < 16; ++ks) {
    __syncthreads();
    *(uint2*)&As[sm * 40 + skq * 4] = pack4(av[0], av[1], av[2], av[3]);
    __syncthreads();

    const short8v a0 = *(const short8v*)&As[lrow * 40 + lgrp * 8];
    const short8v a1 = *(const short8v*)&As[(16 + lrow) * 40 + lgrp * 8];

    if (ks < 15) {
      const int k0 = (ks + 1) * 32;
#pragma unroll
      for (int j = 0; j < 4; ++j) {
        const size_t cioff = (size_t)(k0 + skq * 4 + j) * 16384;
        const float2 p0 = *(const float2*)(x1 + x1base + cioff);
        const float2 p1 = *(const float2*)(x1 + x1base + cioff + 128);
        av[j] = fmaxf(fmaxf(p0.x, p0.y), fmaxf(p1.x, p1.y));
      }
    }

#pragma unroll
    for (int nt = 0; nt < 4; ++nt) {
      const int ntile = wv * 4 + nt;
      const short8v b = *(const short8v*)&wchB[(size_t)((ks * 16 + ntile) * 64 + lane) * 8];
      acc[0][nt] = __builtin_amdgcn_mfma_f32_16x16x32_bf16(a0, b, acc[0][nt], 0, 0, 0);
      acc[1][nt] = __builtin_amdgcn_mfma_f32_16x16x32_bf16(a1, b, acc[1][nt], 0, 0, 0);
    }
  }

  // ---- epilogue A: +bias -> bf16; write to global x1c AND LDS As2[m][ci]
#pragma unroll
  for (int nt = 0; nt < 4; ++nt) {
    const int co = wv * 64 + nt * 16 + lrow;
    const float bias = bch[co];
#pragma unroll
    for (int mt = 0; mt < 2; ++mt) {
      const f32x4 v = acc[mt][nt];
      const uint2 pk = pack4(v.x + bias, v.y + bias, v.z + bias, v.w + bias);
      *(uint2*)&x1c[((size_t)(n * C2 + co)) * HWSZ + hw0 + mt * 16 + lgrp * 4] = pk;
      const int mb = mt * 16 + lgrp * 4;
      As2[(mb + 0) * P2 + co] = (unsigned short)(pk.x & 0xffffu);
      As2[(mb + 1) * P2 + co] = (unsigned short)(pk.x >> 16);
      As2[(mb + 2) * P2 + co] = (unsigned short)(pk.y & 0xffffu);
      As2[(mb + 3) * P2 + co] = (unsigned short)(pk.y >> 16);
      // re-init for phase B
      acc[mt][nt] = (f32x4){0.f, 0.f, 0.f, 0.f};
    }
  }
  __syncthreads();   // As2 complete

  // ================= phase B: concat + conv1x1(w_cc1) + BN + ReLU ==========
  const int ch = tid >> 3;        // staged channel-within-BK (0..31)
  const int mq = (tid & 7) * 4;   // staged m-quad base

  // prefetch x2 for ks=8
  float4 cf = *(const float4*)&x2[((size_t)(n * C2 + ch)) * HWSZ + hw0 + mq];

  // ks 0..7: A-operand = phase A result, straight from As2
#pragma unroll
  for (int ks = 0; ks < 8; ++ks) {
    const short8v a0 = *(const short8v*)&As2[lrow * P2 + ks * 32 + lgrp * 8];
    const short8v a1 = *(const short8v*)&As2[(16 + lrow) * P2 + ks * 32 + lgrp * 8];
#pragma unroll
    for (int nt = 0; nt < 4; ++nt) {
      const int ntile = wv * 4 + nt;
      const short8v b = *(const short8v*)&wcc1B[(size_t)((ks * 16 + ntile) * 64 + lane) * 8];
      acc[0][nt] = __builtin_amdgcn_mfma_f32_16x16x32_bf16(a0, b, acc[0][nt], 0, 0, 0);
      acc[1][nt] = __builtin_amdgcn_mfma_f32_16x16x32_bf16(a1, b, acc[1][nt], 0, 0, 0);
    }
  }

  // ks 8..15: A-operand = x2, staged via As
  for (int ks = 8; ks < 16; ++ks) {
    unsigned short pk[4];
    pk[0] = f2bf(cf.x); pk[1] = f2bf(cf.y); pk[2] = f2bf(cf.z); pk[3] = f2bf(cf.w);
    if (ks < 15) {
      cf = *(const float4*)&x2[((size_t)(n * C2 + (ks - 7) * 32 + ch)) * HWSZ + hw0 + mq];
    }
    __syncthreads();
    As[(mq + 0) * 40 + ch] = pk[0];
    As[(mq + 1) * 40 + ch] = pk[1];
    As[(mq + 2) * 40 + ch] = pk[2];
    As[(mq + 3) * 40 + ch] = pk[3];
    __syncthreads();

    const short8v a0 = *(const short8v*)&As[lrow * 40 + lgrp * 8];
    const short8v a1 = *(const short8v*)&As[(16 + lrow) * 40 + lgrp * 8];
#pragma unroll
    for (int nt = 0; nt < 4; ++nt) {
      const int ntile = wv * 4 + nt;
      const short8v b = *(const short8v*)&wcc1B[(size_t)((ks * 16 + ntile) * 64 + lane) * 8];
      acc[0][nt] = __builtin_amdgcn_mfma_f32_16x16x32_bf16(a0, b, acc[0][nt], 0, 0, 0);
      acc[1][nt] = __builtin_amdgcn_mfma_f32_16x16x32_bf16(a1, b, acc[1][nt], 0, 0, 0);
    }
  }

  // ---- epilogue B: BN + ReLU -> bf16 xbn
#pragma unroll
  for (int nt = 0; nt < 4; ++nt) {
    const int co = wv * 64 + nt * 16 + lrow;
    const float sc = gamma[co] * rsqrtf(var[co] + BN_EPS);
    const float sh = beta[co] - mean[co] * sc;
#pragma unroll
    for (int mt = 0; mt < 2; ++mt) {
      const f32x4 vv = acc[mt][nt];
      *(uint2*)&xbn[((size_t)(n * C2 + co)) * HWSZ + hw0 + mt * 16 + lgrp * 4] =
          pack4(fmaxf(vv.x * sc + sh, 0.f), fmaxf(vv.y * sc + sh, 0.f),
                fmaxf(vv.z * sc + sh, 0.f), fmaxf(vv.w * sc + sh, 0.f));
    }
  }
}

// ---------------------------------------------------------------------------
// K34: fused conv3x3(pad1) -> flow (in LDS) -> dual grid_sample + add -> out
// Block = (n, h). 1024 threads: wl = tid&63 (w), q = tid>>6 (0..15).
// Phase 1: conv via wave-shuffle neighbors; weights LDS-reordered [ci][dy][dx][f].
// Phase 2: sampling, 16 channels per thread.
// ---------------------------------------------------------------------------
__global__ __launch_bounds__(1024) void k34_conv_sample(
    const bf16* __restrict__ xbn, const float* __restrict__ wcc2,
    const bf16* __restrict__ x1c, const float* __restrict__ x2,
    float* __restrict__ out) {
  __shared__ float wsm[9216];          // [ci][dy][dx][f]
  __shared__ float part[16][4][64];
  __shared__ float flr[4][64];
  const int tid = threadIdx.x;
  const int n = blockIdx.x >> 6;
  const int h = blockIdx.x & 63;
  const int wl = tid & 63;
  const int q = tid >> 6;

  // load + reorder weights: src wcc2[f][ci][dy][dx]
  for (int idx = tid; idx < 9216; idx += 1024) {
    const int f = idx / 2304;
    const int r = idx % 2304;
    const int ci = r / 9;
    const int t = r % 9;
    wsm[ci * 36 + (t / 3) * 12 + (t % 3) * 4 + f] = wcc2[idx];
  }
  __syncthreads();

  // ---- phase 1: conv3x3, each q-group handles 16 channels
  float acc[4] = {0.f, 0.f, 0.f, 0.f};
  {
    const bf16* base = xbn + ((size_t)(n * C2 + q * 16)) * HWSZ;
    const float* wq = wsm + (q * 16) * 36;
    for (int cc = 0; cc < 16; ++cc) {
      const bf16* src = base + (size_t)cc * HWSZ;
      const float* wc = wq + cc * 36;
#pragma unroll
      for (int dy = 0; dy < 3; ++dy) {
        const int y = h + dy - 1;
        if ((unsigned)y >= 64u) continue;
        const float v = b2f(src[y * 64 + wl]);
        float vm = __shfl_up(v, 1);
        float vp = __shfl_down(v, 1);
        if (wl == 0) vm = 0.f;
        if (wl == 63) vp = 0.f;
        const float4 wa = *(const float4*)&wc[dy * 12 + 0];
        const float4 wb = *(const float4*)&wc[dy * 12 + 4];
        const float4 wd = *(const float4*)&wc[dy * 12 + 8];
        acc[0] = fmaf(vm, wa.x, fmaf(v, wb.x, fmaf(vp, wd.x, acc[0])));
        acc[1] = fmaf(vm, wa.y, fmaf(v, wb.y, fmaf(vp, wd.y, acc[1])));
        acc[2] = fmaf(vm, wa.z, fmaf(v, wb.z, fmaf(vp, wd.z, acc[2])));
        acc[3] = fmaf(vm, wa.w, fmaf(v, wb.w, fmaf(vp, wd.w, acc[3])));
      }
    }
  }
  part[q][0][wl] = acc[0];
  part[q][1][wl] = acc[1];
  part[q][2][wl] = acc[2];
  part[q][3][wl] = acc[3];
  __syncthreads();
  if (tid < 256) {
    const int f = tid >> 6;
    const int ww = tid & 63;
    float s = 0.f;
#pragma unroll
    for (int qq = 0; qq < 16; ++qq) s += part[qq][f][ww];
    flr[f][ww] = s;
  }
  __syncthreads();

  // ---- phase 2: dual grid_sample + add (ix = w + fx, iy = h + fy)
  const float fx1 = flr[0][wl];
  const float fy1 = flr[1][wl];
  const float fx2 = flr[2][wl];
  const float fy2 = flr[3][wl];

  int oA1, oB1, oC1, oD1; float wa1, wb1, wc1, wd1;
  {
    const float ix = (float)wl + fx1, iy = (float)h + fy1;
    const float x0f = floorf(ix), y0f = floorf(iy);
    const float fx = ix - x0f, fy = iy - y0f;
    const int x0 = (int)x0f, y0 = (int)y0f, x1i = x0 + 1, y1i = y0 + 1;
    const float vx0 = (x0 >= 0 && x0 < 64) ? 1.f : 0.f;
    const float vx1 = (x1i >= 0 && x1i < 64) ? 1.f : 0.f;
    const float vy0 = (y0 >= 0 && y0 < 64) ? 1.f : 0.f;
    const float vy1 = (y1i >= 0 && y1i < 64) ? 1.f : 0.f;
    const int cx0 = min(max(x0, 0), 63), cx1 = min(max(x1i, 0), 63);
    const int cy0 = min(max(y0, 0), 63), cy1 = min(max(y1i, 0), 63);
    oA1 = cy0 * 64 + cx0; oB1 = cy0 * 64 + cx1;
    oC1 = cy1 * 64 + cx0; oD1 = cy1 * 64 + cx1;
    wa1 = (1.f - fx) * (1.f - fy) * vx0 * vy0;
    wb1 = fx * (1.f - fy) * vx1 * vy0;
    wc1 = (1.f - fx) * fy * vx0 * vy1;
    wd1 = fx * fy * vx1 * vy1;
  }
  int oA2, oB2, oC2, oD2; float wa2, wb2, wc2, wd2;
  {
    const float ix = (float)wl + fx2, iy = (float)h + fy2;
    const float x0f = floorf(ix), y0f = floorf(iy);
    const float fx = ix - x0f, fy = iy - y0f;
    const int x0 = (int)x0f, y0 = (int)y0f, x1i = x0 + 1, y1i = y0 + 1;
    const float vx0 = (x0 >= 0 && x0 < 64) ? 1.f : 0.f;
    const float vx1 = (x1i >= 0 && x1i < 64) ? 1.f : 0.f;
    const float vy0 = (y0 >= 0 && y0 < 64) ? 1.f : 0.f;
    const float vy1 = (y1i >= 0 && y1i < 64) ? 1.f : 0.f;
    const int cx0 = min(max(x0, 0), 63), cx1 = min(max(x1i, 0), 63);
    const int cy0 = min(max(y0, 0), 63), cy1 = min(max(y1i, 0), 63);
    oA2 = cy0 * 64 + cx0; oB2 = cy0 * 64 + cx1;
    oC2 = cy1 * 64 + cx0; oD2 = cy1 * 64 + cx1;
    wa2 = (1.f - fx) * (1.f - fy) * vx0 * vy0;
    wb2 = fx * (1.f - fy) * vx1 * vy0;
    wc2 = (1.f - fx) * fy * vx0 * vy1;
    wd2 = fx * fy * vx1 * vy1;
  }

  const bf16*  p1 = x1c + ((size_t)n * C2) * HWSZ;
  const float* p2 = x2 + ((size_t)n * C2) * HWSZ;
  const size_t obase = ((size_t)n * C2) * HWSZ + h * 64 + wl;
#pragma unroll 4
  for (int i = 0; i < 16; ++i) {
    const int co = q * 16 + i;
    const bf16*  q1 = p1 + (size_t)co * HWSZ;
    const float* q2 = p2 + (size_t)co * HWSZ;
    const float u = b2f(q1[oA1]) * wa1 + b2f(q1[oB1]) * wb1 + b2f(q1[oC1]) * wc1 + b2f(q1[oD1]) * wd1
                  + q2[oA2] * wa2 + q2[oB2] * wb2 + q2[oC2] * wc2 + q2[oD2] * wd2;
    out[obase + (size_t)co * HWSZ] = u;
  }
}

// ---------------------------------------------------------------------------
extern "C" void kernel_launch(void* const* d_in, const int* in_sizes, int n_in,
                              void* d_out, int out_size, void* d_ws, size_t ws_size,
                              hipStream_t stream) {
  const float* x1      = (const float*)d_in[0];
  const float* x2      = (const float*)d_in[1];
  const float* w_change= (const float*)d_in[2];
  const float* b_change= (const float*)d_in[3];
  const float* w_cc1   = (const float*)d_in[4];
  const float* bn_gamma= (const float*)d_in[5];
  const float* bn_beta = (const float*)d_in[6];
  const float* bn_mean = (const float*)d_in[7];
  const float* bn_var  = (const float*)d_in[8];
  const float* w_cc2   = (const float*)d_in[9];
  float* out = (float*)d_out;   // fp32 output

  // workspace (~33 MiB):
  //   x1c  : bf16, 8388608 elems (16 MiB) @ 0
  //   xbn  : bf16, 8388608 elems (16 MiB) @ 16 MiB
  //   wchB : bf16, 131072 elems (256 KiB) @ 32 MiB
  //   wcc1B: bf16, 131072 elems (256 KiB) @ 32 MiB + 256 KiB
  bf16*           x1c   = (bf16*)d_ws;
  bf16*           xbn   = (bf16*)((char*)d_ws + (16u << 20));
  unsigned short* wchB  = (unsigned short*)((char*)d_ws + (32u << 20));
  unsigned short* wcc1B = (unsigned short*)((char*)d_ws + (32u << 20) + (256u << 10));

  k0_swizzle<<<1024, 256, 0, stream>>>(w_change, w_cc1, wchB, wcc1B);
  k12_fused<<<1024, 256, 0, stream>>>(x1, x2, wchB, wcc1B, b_change,
                                      bn_gamma, bn_beta, bn_mean, bn_var,
                                      x1c, xbn);
  k34_conv_sample<<<512, 1024, 0, stream>>>(xbn, w_cc2, x1c, x2, out);
}

// Round 8
// 146.194 us; speedup vs baseline: 2.6572x; 1.0291x over previous
//
#include <hip/hip_runtime.h>
#include <hip/hip_bf16.h>

#define NB 8
#define C1 512
#define C2 256
#define HWSZ 4096
#define BN_EPS 1e-5f
#define P2 264   // As2 pitch in ushorts

typedef __hip_bfloat16 bf16;
typedef __hip_bfloat162 bf162;
typedef __attribute__((ext_vector_type(8))) short short8v;
typedef __attribute__((ext_vector_type(4))) float f32x4;

static __device__ inline float b2f(bf16 h) { return __bfloat162float(h); }

static __device__ inline unsigned short f2bf(float f) {
  union { bf16 h; unsigned short u; } c;
  c.h = __float2bfloat16(f);
  return c.u;
}

static __device__ inline unsigned pack2(float a, float b) {
  union { unsigned u; bf162 h; } pk;
  pk.h = __float22bfloat162_rn(make_float2(a, b));
  return pk.u;
}

static __device__ inline uint2 pack4(float a, float b, float c, float d) {
  union { uint2 u; bf162 h[2]; } pk;
  pk.h[0] = __float22bfloat162_rn(make_float2(a, b));
  pk.h[1] = __float22bfloat162_rn(make_float2(c, d));
  return pk.u;
}

// SBARQ: drain THIS wave's LDS ops (reads incl.) then barrier — prevents the
// WAR race on LDS re-write while leaving global (vmcnt) prefetch in flight.
#define SBARQ() asm volatile("s_waitcnt lgkmcnt(0)\n\ts_barrier" ::: "memory")
// publish barrier: writes complete (lgkmcnt) then barrier.
#define SBAR()  asm volatile("s_barrier" ::: "memory")
#define LGKM0() asm volatile("s_waitcnt lgkmcnt(0)" ::: "memory")

// ---------------------------------------------------------------------------
// K0: swizzle weights into MFMA B-fragment order (bf16).
// ---------------------------------------------------------------------------
__global__ __launch_bounds__(256) void k0_swizzle(
    const float* __restrict__ wch, const float* __restrict__ wcc1,
    unsigned short* __restrict__ wchB, unsigned short* __restrict__ wcc1B) {
  const int t = blockIdx.x * 256 + threadIdx.x;   // 0 .. 262143
  const int which = t >> 17;
  const int r = t & 131071;
  const int i = r & 7;
  const int lane = (r >> 3) & 63;
  const int ntile = (r >> 9) & 15;
  const int kstep = r >> 13;                      // 0..15
  const int ci = kstep * 32 + (lane >> 4) * 8 + i;
  const int co = ntile * 16 + (lane & 15);
  const float* s = which ? wcc1 : wch;
  unsigned short* d = which ? wcc1B : wchB;
  d[r] = f2bf(s[co * 512 + ci]);
}

// ---------------------------------------------------------------------------
// K12: fused [maxpool2x2 + conv1x1 + bias] -> x1c, then
//            [concat + conv1x1 + BN + ReLU] -> xbn (bf16)
// Phase A: float4 staging loads, depth-2 register prefetch, raw barriers
// (SBARQ fixes the round-7 LDS WAR race while keeping vmcnt free).
// ---------------------------------------------------------------------------
__global__ __launch_bounds__(256) void k12_fused(
    const float* __restrict__ x1, const float* __restrict__ x2,
    const unsigned short* __restrict__ wchB, const unsigned short* __restrict__ wcc1B,
    const float* __restrict__ bch,
    const float* __restrict__ gamma, const float* __restrict__ beta,
    const float* __restrict__ mean, const float* __restrict__ var,
    bf16* __restrict__ x1c, bf16* __restrict__ xbn) {
  __shared__ unsigned short As[32 * 40];     // staging tile [m][k], pitch 40
  __shared__ unsigned short As2[32 * P2];    // phase A output = phase B A-operand
  const int tid = threadIdx.x;
  const int lane = tid & 63;
  const int wv = tid >> 6;
  const int lrow = lane & 15;
  const int lgrp = lane >> 4;

  const int m0g = blockIdx.x * 32;
  const int n = m0g >> 12;
  const int hw0 = m0g & 4095;
  const int h = hw0 >> 6;
  const int w0 = hw0 & 63;

  f32x4 acc[2][4];
#pragma unroll
  for (int mt = 0; mt < 2; ++mt)
#pragma unroll
    for (int nt = 0; nt < 4; ++nt) acc[mt][nt] = (f32x4){0.f, 0.f, 0.f, 0.f};

  // ================= phase A: maxpool + conv1x1(w_change) =================
  const int pmi = tid & 15;        // m-pair index -> ms = 2*pmi
  const int ms = pmi * 2;
  const int ch0 = (tid >> 4) * 2;  // channel pair base (0,2,..,30)

  const float* x1p = x1 + (size_t)n * C1 * 16384 + (size_t)(2 * h) * 128 + 2 * (w0 + ms);

  float4 t0, b0, t1, b1;   // in-flight raw (one K-step's patch)
#define LOADA(K0_) do { \
    const float* p_ = x1p + (size_t)((K0_) + ch0) * 16384; \
    t0 = *(const float4*)p_;            b0 = *(const float4*)(p_ + 128); \
    t1 = *(const float4*)(p_ + 16384);  b1 = *(const float4*)(p_ + 16384 + 128); \
  } while (0)
#define POOLA(U0_, U1_) do { \
    U0_ = pack2(fmaxf(fmaxf(t0.x, t0.y), fmaxf(b0.x, b0.y)), \
                fmaxf(fmaxf(t1.x, t1.y), fmaxf(b1.x, b1.y))); \
    U1_ = pack2(fmaxf(fmaxf(t0.z, t0.w), fmaxf(b0.z, b0.w)), \
                fmaxf(fmaxf(t1.z, t1.w), fmaxf(b1.z, b1.w))); \
  } while (0)

  unsigned uA0, uA1;
  LOADA(0);
  POOLA(uA0, uA1);
  LOADA(32);               // ks=1 in flight

  for (int ks = 0; ks < 16; ++ks) {
    SBARQ();                                  // all waves' As READS drained
    *(unsigned*)&As[ms * 40 + ch0] = uA0;
    *(unsigned*)&As[(ms + 1) * 40 + ch0] = uA1;
    LGKM0();
    SBAR();                                   // writes visible

    unsigned uN0, uN1;
    if (ks < 15) {
      POOLA(uN0, uN1);                        // pool ks+1 (auto vmcnt wait)
      if (ks < 14) LOADA((ks + 2) * 32);      // issue ks+2
    }

    const short8v a0 = *(const short8v*)&As[lrow * 40 + lgrp * 8];
    const short8v a1 = *(const short8v*)&As[(16 + lrow) * 40 + lgrp * 8];
#pragma unroll
    for (int nt = 0; nt < 4; ++nt) {
      const int ntile = wv * 4 + nt;
      const short8v b = *(const short8v*)&wchB[(size_t)((ks * 16 + ntile) * 64 + lane) * 8];
      acc[0][nt] = __builtin_amdgcn_mfma_f32_16x16x32_bf16(a0, b, acc[0][nt], 0, 0, 0);
      acc[1][nt] = __builtin_amdgcn_mfma_f32_16x16x32_bf16(a1, b, acc[1][nt], 0, 0, 0);
    }
    if (ks < 15) { uA0 = uN0; uA1 = uN1; }
  }

  // ---- prefetch x2 for phase B's staged half (channels 0..63 of x2)
  const int chB = tid >> 3;        // 0..31
  const int mqB = (tid & 7) * 4;
  float4 cf0 = *(const float4*)&x2[((size_t)(n * C2 + chB)) * HWSZ + hw0 + mqB];
  float4 cf1 = *(const float4*)&x2[((size_t)(n * C2 + 32 + chB)) * HWSZ + hw0 + mqB];

  // ---- epilogue A: +bias -> bf16; write global x1c AND LDS As2[m][ci]
#pragma unroll
  for (int nt = 0; nt < 4; ++nt) {
    const int co = wv * 64 + nt * 16 + lrow;
    const float bias = bch[co];
#pragma unroll
    for (int mt = 0; mt < 2; ++mt) {
      const f32x4 v = acc[mt][nt];
      const uint2 pk = pack4(v.x + bias, v.y + bias, v.z + bias, v.w + bias);
      *(uint2*)&x1c[((size_t)(n * C2 + co)) * HWSZ + hw0 + mt * 16 + lgrp * 4] = pk;
      const int mb = mt * 16 + lgrp * 4;
      As2[(mb + 0) * P2 + co] = (unsigned short)(pk.x & 0xffffu);
      As2[(mb + 1) * P2 + co] = (unsigned short)(pk.x >> 16);
      As2[(mb + 2) * P2 + co] = (unsigned short)(pk.y & 0xffffu);
      As2[(mb + 3) * P2 + co] = (unsigned short)(pk.y >> 16);
      acc[mt][nt] = (f32x4){0.f, 0.f, 0.f, 0.f};
    }
  }
  LGKM0();
  SBAR();   // As2 complete

  // ================= phase B: concat + conv1x1(w_cc1) + BN + ReLU ==========
  // ks 0..7: A-operand = phase A result, straight from As2
#pragma unroll
  for (int ks = 0; ks < 8; ++ks) {
    const short8v a0 = *(const short8v*)&As2[lrow * P2 + ks * 32 + lgrp * 8];
    const short8v a1 = *(const short8v*)&As2[(16 + lrow) * P2 + ks * 32 + lgrp * 8];
#pragma unroll
    for (int nt = 0; nt < 4; ++nt) {
      const int ntile = wv * 4 + nt;
      const short8v b = *(const short8v*)&wcc1B[(size_t)((ks * 16 + ntile) * 64 + lane) * 8];
      acc[0][nt] = __builtin_amdgcn_mfma_f32_16x16x32_bf16(a0, b, acc[0][nt], 0, 0, 0);
      acc[1][nt] = __builtin_amdgcn_mfma_f32_16x16x32_bf16(a1, b, acc[1][nt], 0, 0, 0);
    }
  }

  // ks 8..15: A-operand = x2, staged via As; double-buffered prefetch
  for (int ks = 8; ks < 16; ++ks) {
    const unsigned p0 = pack2(cf0.x, cf0.y);
    const unsigned p1 = pack2(cf0.z, cf0.w);
    cf0 = cf1;
    if (ks < 14) {
      cf1 = *(const float4*)&x2[((size_t)(n * C2 + (ks - 6) * 32 + chB)) * HWSZ + hw0 + mqB];
    }
    SBARQ();                                  // prior As reads drained
    As[(mqB + 0) * 40 + chB] = (unsigned short)(p0 & 0xffffu);
    As[(mqB + 1) * 40 + chB] = (unsigned short)(p0 >> 16);
    As[(mqB + 2) * 40 + chB] = (unsigned short)(p1 & 0xffffu);
    As[(mqB + 3) * 40 + chB] = (unsigned short)(p1 >> 16);
    LGKM0();
    SBAR();

    const short8v a0 = *(const short8v*)&As[lrow * 40 + lgrp * 8];
    const short8v a1 = *(const short8v*)&As[(16 + lrow) * 40 + lgrp * 8];
#pragma unroll
    for (int nt = 0; nt < 4; ++nt) {
      const int ntile = wv * 4 + nt;
      const short8v b = *(const short8v*)&wcc1B[(size_t)((ks * 16 + ntile) * 64 + lane) * 8];
      acc[0][nt] = __builtin_amdgcn_mfma_f32_16x16x32_bf16(a0, b, acc[0][nt], 0, 0, 0);
      acc[1][nt] = __builtin_amdgcn_mfma_f32_16x16x32_bf16(a1, b, acc[1][nt], 0, 0, 0);
    }
  }

  // ---- epilogue B: BN + ReLU -> bf16 xbn
#pragma unroll
  for (int nt = 0; nt < 4; ++nt) {
    const int co = wv * 64 + nt * 16 + lrow;
    const float sc = gamma[co] * rsqrtf(var[co] + BN_EPS);
    const float sh = beta[co] - mean[co] * sc;
#pragma unroll
    for (int mt = 0; mt < 2; ++mt) {
      const f32x4 vv = acc[mt][nt];
      *(uint2*)&xbn[((size_t)(n * C2 + co)) * HWSZ + hw0 + mt * 16 + lgrp * 4] =
          pack4(fmaxf(vv.x * sc + sh, 0.f), fmaxf(vv.y * sc + sh, 0.f),
                fmaxf(vv.z * sc + sh, 0.f), fmaxf(vv.w * sc + sh, 0.f));
    }
  }
#undef LOADA
#undef POOLA
}

// ---------------------------------------------------------------------------
// K34: fused conv3x3(pad1) -> flow (in LDS) -> dual grid_sample + add -> out
// ---------------------------------------------------------------------------
__global__ __launch_bounds__(1024) void k34_conv_sample(
    const bf16* __restrict__ xbn, const float* __restrict__ wcc2,
    const bf16* __restrict__ x1c, const float* __restrict__ x2,
    float* __restrict__ out) {
  __shared__ float wsm[9216];          // [ci][dy][dx][f]
  __shared__ float part[16][4][64];
  __shared__ float flr[4][64];
  const int tid = threadIdx.x;
  const int n = blockIdx.x >> 6;
  const int h = blockIdx.x & 63;
  const int wl = tid & 63;
  const int q = tid >> 6;

  for (int idx = tid; idx < 9216; idx += 1024) {
    const int f = idx / 2304;
    const int r = idx % 2304;
    const int ci = r / 9;
    const int t = r % 9;
    wsm[ci * 36 + (t / 3) * 12 + (t % 3) * 4 + f] = wcc2[idx];
  }
  __syncthreads();

  float acc[4] = {0.f, 0.f, 0.f, 0.f};
  {
    const bf16* base = xbn + ((size_t)(n * C2 + q * 16)) * HWSZ;
    const float* wq = wsm + (q * 16) * 36;
    for (int cc = 0; cc < 16; ++cc) {
      const bf16* src = base + (size_t)cc * HWSZ;
      const float* wc = wq + cc * 36;
#pragma unroll
      for (int dy = 0; dy < 3; ++dy) {
        const int y = h + dy - 1;
        if ((unsigned)y >= 64u) continue;
        const float v = b2f(src[y * 64 + wl]);
        float vm = __shfl_up(v, 1);
        float vp = __shfl_down(v, 1);
        if (wl == 0) vm = 0.f;
        if (wl == 63) vp = 0.f;
        const float4 wa = *(const float4*)&wc[dy * 12 + 0];
        const float4 wb = *(const float4*)&wc[dy * 12 + 4];
        const float4 wd = *(const float4*)&wc[dy * 12 + 8];
        acc[0] = fmaf(vm, wa.x, fmaf(v, wb.x, fmaf(vp, wd.x, acc[0])));
        acc[1] = fmaf(vm, wa.y, fmaf(v, wb.y, fmaf(vp, wd.y, acc[1])));
        acc[2] = fmaf(vm, wa.z, fmaf(v, wb.z, fmaf(vp, wd.z, acc[2])));
        acc[3] = fmaf(vm, wa.w, fmaf(v, wb.w, fmaf(vp, wd.w, acc[3])));
      }
    }
  }
  part[q][0][wl] = acc[0];
  part[q][1][wl] = acc[1];
  part[q][2][wl] = acc[2];
  part[q][3][wl] = acc[3];
  __syncthreads();
  if (tid < 256) {
    const int f = tid >> 6;
    const int ww = tid & 63;
    float s = 0.f;
#pragma unroll
    for (int qq = 0; qq < 16; ++qq) s += part[qq][f][ww];
    flr[f][ww] = s;
  }
  __syncthreads();

  const float fx1 = flr[0][wl];
  const float fy1 = flr[1][wl];
  const float fx2 = flr[2][wl];
  const float fy2 = flr[3][wl];

  int oA1, oB1, oC1, oD1; float wa1, wb1, wc1, wd1;
  {
    const float ix = (float)wl + fx1, iy = (float)h + fy1;
    const float x0f = floorf(ix), y0f = floorf(iy);
    const float fx = ix - x0f, fy = iy - y0f;
    const int x0 = (int)x0f, y0 = (int)y0f, x1i = x0 + 1, y1i = y0 + 1;
    const float vx0 = (x0 >= 0 && x0 < 64) ? 1.f : 0.f;
    const float vx1 = (x1i >= 0 && x1i < 64) ? 1.f : 0.f;
    const float vy0 = (y0 >= 0 && y0 < 64) ? 1.f : 0.f;
    const float vy1 = (y1i >= 0 && y1i < 64) ? 1.f : 0.f;
    const int cx0 = min(max(x0, 0), 63), cx1 = min(max(x1i, 0), 63);
    const int cy0 = min(max(y0, 0), 63), cy1 = min(max(y1i, 0), 63);
    oA1 = cy0 * 64 + cx0; oB1 = cy0 * 64 + cx1;
    oC1 = cy1 * 64 + cx0; oD1 = cy1 * 64 + cx1;
    wa1 = (1.f - fx) * (1.f - fy) * vx0 * vy0;
    wb1 = fx * (1.f - fy) * vx1 * vy0;
    wc1 = (1.f - fx) * fy * vx0 * vy1;
    wd1 = fx * fy * vx1 * vy1;
  }
  int oA2, oB2, oC2, oD2; float wa2, wb2, wc2, wd2;
  {
    const float ix = (float)wl + fx2, iy = (float)h + fy2;
    const float x0f = floorf(ix), y0f = floorf(iy);
    const float fx = ix - x0f, fy = iy - y0f;
    const int x0 = (int)x0f, y0 = (int)y0f, x1i = x0 + 1, y1i = y0 + 1;
    const float vx0 = (x0 >= 0 && x0 < 64) ? 1.f : 0.f;
    const float vx1 = (x1i >= 0 && x1i < 64) ? 1.f : 0.f;
    const float vy0 = (y0 >= 0 && y0 < 64) ? 1.f : 0.f;
    const float vy1 = (y1i >= 0 && y1i < 64) ? 1.f : 0.f;
    const int cx0 = min(max(x0, 0), 63), cx1 = min(max(x1i, 0), 63);
    const int cy0 = min(max(y0, 0), 63), cy1 = min(max(y1i, 0), 63);
    oA2 = cy0 * 64 + cx0; oB2 = cy0 * 64 + cx1;
    oC2 = cy1 * 64 + cx0; oD2 = cy1 * 64 + cx1;
    wa2 = (1.f - fx) * (1.f - fy) * vx0 * vy0;
    wb2 = fx * (1.f - fy) * vx1 * vy0;
    wc2 = (1.f - fx) * fy * vx0 * vy1;
    wd2 = fx * fy * vx1 * vy1;
  }

  const bf16*  p1 = x1c + ((size_t)n * C2) * HWSZ;
  const float* p2 = x2 + ((size_t)n * C2) * HWSZ;
  const size_t obase = ((size_t)n * C2) * HWSZ + h * 64 + wl;
#pragma unroll 4
  for (int i = 0; i < 16; ++i) {
    const int co = q * 16 + i;
    const bf16*  q1 = p1 + (size_t)co * HWSZ;
    const float* q2 = p2 + (size_t)co * HWSZ;
    const float u = b2f(q1[oA1]) * wa1 + b2f(q1[oB1]) * wb1 + b2f(q1[oC1]) * wc1 + b2f(q1[oD1]) * wd1
                  + q2[oA2] * wa2 + q2[oB2] * wb2 + q2[oC2] * wc2 + q2[oD2] * wd2;
    out[obase + (size_t)co * HWSZ] = u;
  }
}

// ---------------------------------------------------------------------------
extern "C" void kernel_launch(void* const* d_in, const int* in_sizes, int n_in,
                              void* d_out, int out_size, void* d_ws, size_t ws_size,
                              hipStream_t stream) {
  const float* x1      = (const float*)d_in[0];
  const float* x2      = (const float*)d_in[1];
  const float* w_change= (const float*)d_in[2];
  const float* b_change= (const float*)d_in[3];
  const float* w_cc1   = (const float*)d_in[4];
  const float* bn_gamma= (const float*)d_in[5];
  const float* bn_beta = (const float*)d_in[6];
  const float* bn_mean = (const float*)d_in[7];
  const float* bn_var  = (const float*)d_in[8];
  const float* w_cc2   = (const float*)d_in[9];
  float* out = (float*)d_out;

  bf16*           x1c   = (bf16*)d_ws;
  bf16*           xbn   = (bf16*)((char*)d_ws + (16u << 20));
  unsigned short* wchB  = (unsigned short*)((char*)d_ws + (32u << 20));
  unsigned short* wcc1B = (unsigned short*)((char*)d_ws + (32u << 20) + (256u << 10));

  k0_swizzle<<<1024, 256, 0, stream>>>(w_change, w_cc1, wchB, wcc1B);
  k12_fused<<<1024, 256, 0, stream>>>(x1, x2, wchB, wcc1B, b_change,
                                      bn_gamma, bn_beta, bn_mean, bn_var,
                                      x1c, xbn);
  k34_conv_sample<<<512, 1024, 0, stream>>>(xbn, w_cc2, x1c, x2, out);
}